// Round 7
// baseline (278.722 us; speedup 1.0000x reference)
//
#include <hip/hip_runtime.h>
#include <cstdint>
#include <cstddef>

#define BB 32
#define NN 8400
#define NCC 80
#define MM 40
#define RM 16
#define TOPKK 10
#define CAP 2048      // max positives per (b,m) global list
#define SEG 32        // LDS stage slots per m per 128-anchor block
#define SLOTW 40      // dense slot width (halfwords) in global scs
#define SLOTP 42      // padded LDS halfword stride in k_align (21 dwords, gcd(21,32)=1)

// ---------- helpers ----------
__device__ __forceinline__ void anchor_xy(int n, float& ax, float& ay) {
    int s, x, y;
    if (n < 6400)      { s = 8;  y = n / 80;            x = n - y * 80; }
    else if (n < 8000) { int i = n - 6400; s = 16; y = i / 40; x = i - y * 40; }
    else               { int i = n - 8000; s = 32; y = i / 20; x = i - y * 20; }
    ax = ((float)x + 0.5f) * (float)s;
    ay = ((float)y + 0.5f) * (float)s;
}

// ---------- K_score: streaming pass over ps+pd ----------
// grid: (132, B) x 256 thr; tile = 64 anchors. Does: DFL->pbb, softplus sum,
// sqrt(sigmoid) for label classes -> dense fp16 scs (B,N,40). Two input
// streams in flight at once; 3 barriers; ~7 KB LDS -> high occupancy.
__global__ __launch_bounds__(256) void k_score(const float* __restrict__ ps,
                                               const float* __restrict__ pd,
                                               const int*   __restrict__ gl,
                                               const float* __restrict__ w,
                                               float* __restrict__ pbb,
                                               unsigned* __restrict__ scs,
                                               float* __restrict__ accum) {
    __shared__ _Float16 sst[64 * SLOTW];   // 5 KB, dense
    __shared__ float    lt[256];           // DFL ltrb staging
    __shared__ int      cmap[NCC];
    __shared__ int      glab[MM];
    __shared__ float    redf[4];
    const int b  = blockIdx.y;
    const int n0 = blockIdx.x * 64;
    const int t  = threadIdx.x;

    // ---- issue ALL global loads up front (pd + ps streams overlap) ----
    const int a = t >> 2, side = t & 3;                 // thread t = one DFL side
    const int na = min(n0 + a, NN - 1);
    const float* pp = pd + (((size_t)(b * NN + na)) * 4 + side) * RM;
    float4 d0 = *(const float4*)(pp);
    float4 d1 = *(const float4*)(pp + 4);
    float4 d2 = *(const float4*)(pp + 8);
    float4 d3 = *(const float4*)(pp + 12);
    float4 vv[5];
    #pragma unroll
    for (int k = 0; k < 5; k++) {
        int f = t + k * 256;                            // [0,1280)
        int row = f / 20, c4 = f - row * 20;
        int nc = min(n0 + row, NN - 1);
        vv[k] = *(const float4*)(ps + ((size_t)(b * NN + nc)) * NCC + c4 * 4);
    }

    if (t < MM)                 glab[t] = gl[b * MM + t];
    if (t >= 64 && t < 64+NCC)  cmap[t - 64] = 0x7FFFFFFF;
    __syncthreads();
    if (t < MM) atomicMin(&cmap[glab[t]], t);           // label dedup -> slot=rep m

    // ---- DFL softmax-dot (hides remaining ps-load latency) ----
    {
        float x[RM] = {d0.x,d0.y,d0.z,d0.w, d1.x,d1.y,d1.z,d1.w,
                       d2.x,d2.y,d2.z,d2.w, d3.x,d3.y,d3.z,d3.w};
        float mx = x[0];
        #pragma unroll
        for (int i = 1; i < RM; i++) mx = fmaxf(mx, x[i]);
        float s = 0.f, d = 0.f;
        #pragma unroll
        for (int i = 0; i < RM; i++) {
            float e = __builtin_amdgcn_exp2f((x[i] - mx) * 1.44269504f);
            s += e; d += e * w[i];
        }
        lt[t] = d * __builtin_amdgcn_rcpf(s);
    }
    __syncthreads();                                    // lt + cmap ready
    if (t < 64) {
        int n = n0 + t;
        float ax, ay; anchor_xy(min(n, NN - 1), ax, ay);
        float4 l4 = *(const float4*)&lt[t * 4];
        if (n < NN)
            *(float4*)(pbb + (size_t)(b * NN + n) * 4) =
                make_float4(ax - l4.x, ay - l4.y, ax + l4.z, ay + l4.w);
    }

    // ---- scores: softplus sum + sqrt(sigmoid) for slot classes ----
    float sp = 0.f;
    #pragma unroll
    for (int k = 0; k < 5; k++) {
        int f = t + k * 256;
        int row = f / 20, c4 = f - row * 20;
        float vmask = (n0 + row < NN) ? 1.f : 0.f;
        float xs[4] = {vv[k].x, vv[k].y, vv[k].z, vv[k].w};
        #pragma unroll
        for (int j = 0; j < 4; j++) {
            float x = xs[j];
            float e = __builtin_amdgcn_exp2f(-1.44269504f * fabsf(x));
            sp += vmask * (fmaxf(x, 0.f) + 0.69314718f * __builtin_amdgcn_logf(1.0f + e));
            int sl = cmap[c4 * 4 + j];
            if (sl < MM) {
                float r = __builtin_amdgcn_rcpf(1.0f + e);
                float sg = (x >= 0.f) ? r : e * r;
                sst[row * SLOTW + sl] = (_Float16)__builtin_amdgcn_sqrtf(sg);
            }
        }
    }
    __syncthreads();
    // coalesced dword copy-out: 64 rows x 20 dwords
    const unsigned* ss = (const unsigned*)sst;
    size_t gbase = (size_t)(b * NN + n0) * 20;
    #pragma unroll
    for (int k = 0; k < 5; k++) {
        int f = t + k * 256;
        int row = f / 20;
        if (n0 + row < NN) scs[gbase + f] = ss[f];
    }

    // softplus block reduction -> one atomic
    #pragma unroll
    for (int off = 32; off > 0; off >>= 1) sp += __shfl_down(sp, off);
    if ((t & 63) == 0) redf[t >> 6] = sp;
    __syncthreads();
    if (t == 0) atomicAdd(accum, redf[0] + redf[1] + redf[2] + redf[3]);
}

// ---------- K_align: align + sparse push from precomputed tiles ----------
// grid: (66, B) x 256 thr; tile = 128 anchors. No transcendentals but rcp.
__global__ __launch_bounds__(256) void k_align(const unsigned* __restrict__ scs,
                                               const int*   __restrict__ gl,
                                               const float* __restrict__ gb,
                                               const float* __restrict__ pbb,
                                               float* __restrict__ maxm,
                                               int*   __restrict__ cnts,
                                               unsigned long long* __restrict__ lists,
                                               int*   __restrict__ tgt) {
    __shared__ _Float16 sst[128 * SLOTP];            // 10.75 KB padded
    __shared__ float4 box[128];
    __shared__ float  gtb[MM * 4];
    __shared__ int    glab[MM];
    __shared__ int    slotm[MM];
    __shared__ int    cmap[NCC];
    __shared__ unsigned long long stage[MM * SEG];   // 10.24 KB
    __shared__ int    scnt[MM];
    __shared__ int    baseLoc[MM];
    __shared__ float  cm[256];
    const int b  = blockIdx.y;
    const int n0 = blockIdx.x * 128;
    const int t  = threadIdx.x;
    const int bm0 = b * MM;

    // issue tile loads up front
    unsigned sd[10];
    #pragma unroll
    for (int k = 0; k < 10; k++) {
        int f = t + k * 256;                         // [0,2560)
        int row = f / 20, cd = f - row * 20;
        int rc = min(n0 + row, NN - 1);
        sd[k] = scs[(size_t)(b * NN + rc) * 20 + cd];
    }
    float4 bx4 = make_float4(0,0,0,0);
    if (t < 128) bx4 = *(const float4*)(pbb + (size_t)(b * NN + min(n0 + t, NN - 1)) * 4);

    if (t < 128 && n0 + t < NN) tgt[(size_t)b * NN + n0 + t] = 0x7F7F7F7F;
    if (t < MM * 4)              gtb[t] = gb[b * MM * 4 + t];
    if (t >= 192 && t < 192+MM)  glab[t - 192] = gl[b * MM + (t - 192)];
    if (t >= 64 && t < 64+NCC)   cmap[t - 64] = 0x7FFFFFFF;
    if (t >= 144 && t < 144+MM)  scnt[t - 144] = 0;
    __syncthreads();
    if (t < MM) atomicMin(&cmap[glab[t]], t);
    // LDS tile stores (overlap with dedup)
    #pragma unroll
    for (int k = 0; k < 10; k++) {
        int f = t + k * 256;
        int row = f / 20, cd = f - row * 20;
        ((unsigned*)sst)[row * 21 + cd] = sd[k];     // halfword stride 42
    }
    if (t < 128) box[t] = bx4;
    __syncthreads();
    if (t < MM) slotm[t] = cmap[glab[t]];
    __syncthreads();

    // ---- align loop: 20 gts per thread-half; LDS-staged positive push ----
    const int nloc = t & 127;
    const int n    = n0 + nloc;
    const int mb   = (t >> 7) * 20;
    const bool valid = (n < NN);
    float cmax = -INFINITY;
    float4 p4 = box[nloc];
    const float px1 = p4.x, py1 = p4.y, px2 = p4.z, py2 = p4.w;
    const float a1 = (px2 - px1) * (py2 - py1);
    #pragma unroll
    for (int j = 0; j < 20; j++) {
        int m = mb + j;
        float gx1 = gtb[m*4+0], gy1 = gtb[m*4+1], gx2 = gtb[m*4+2], gy2 = gtb[m*4+3];
        float a2 = (gx2 - gx1) * (gy2 - gy1);
        float iw = fmaxf(fminf(px2, gx2) - fmaxf(px1, gx1), 0.f);
        float ih = fmaxf(fminf(py2, gy2) - fmaxf(py1, gy1), 0.f);
        float inter = iw * ih;
        float iou = fmaxf(inter * __builtin_amdgcn_rcpf(a1 + a2 - inter + 1e-16f), 0.f);
        float al = 0.f;
        if (valid) {
            float ssq = (float)sst[nloc * SLOTP + slotm[m]];   // sqrt(sigmoid)
            float i2 = iou * iou;
            al = ssq * (i2 * i2 * i2);
        }
        cmax = fmaxf(cmax, al);
        if (al > 1e-9f) {
            unsigned long long key =
                ((unsigned long long)__float_as_uint(al) << 32) | (unsigned)n;
            int li = atomicAdd(&scnt[m], 1);
            if (li < SEG) stage[m * SEG + li] = key;
            else {                       // rare overflow: direct global push
                int gi = atomicAdd(&cnts[bm0 + m], 1);
                if (gi < CAP) lists[((size_t)(bm0 + m)) * CAP + gi] = key;
            }
        }
    }
    cm[t] = cmax;
    __syncthreads();
    if (t < 128 && valid) maxm[(size_t)b * NN + n] = fmaxf(cm[t], cm[t + 128]);
    if (t < MM) {
        int ns = min(scnt[t], SEG);
        baseLoc[t] = (ns > 0) ? atomicAdd(&cnts[bm0 + t], ns) : 0;
    }
    __syncthreads();
    #pragma unroll
    for (int f = t; f < MM * SEG; f += 256) {
        int m = f >> 5, i = f & 31;
        if (i < min(scnt[m], SEG)) {
            int gi = baseLoc[m] + i;
            if (gi < CAP) lists[((size_t)(bm0 + m)) * CAP + gi] = stage[f];
        }
    }
}

// ---------- K_topk: top-10 of compacted positives, LDS-only passes ----------
__global__ __launch_bounds__(64) void k_topk(const unsigned long long* __restrict__ lists,
                                             const int*   __restrict__ cnts,
                                             const float* __restrict__ maxm,
                                             int* __restrict__ tgt) {
    __shared__ unsigned long long keys[CAP];
    __shared__ unsigned long long sel[TOPKK];
    const int bm = blockIdx.x, b = bm / MM, m = bm % MM, t = threadIdx.x;
    int cnt = min(cnts[bm], CAP);
    int kk = min(TOPKK, cnt);
    for (int i = t; i < cnt; i += 64) {
        unsigned long long L = lists[(size_t)bm * CAP + i];
        keys[i] = (L & 0xFFFFFFFF00000000ull) | (0xFFFFFFFFull - (L & 0xFFFFFFFFull));
    }
    __syncthreads();
    for (int p = 0; p < kk; p++) {
        unsigned long long best = 0ull;
        for (int i = t; i < cnt; i += 64) best = keys[i] > best ? keys[i] : best;
        #pragma unroll
        for (int off = 32; off > 0; off >>= 1) {
            unsigned long long o = __shfl_xor(best, off);
            best = o > best ? o : best;
        }
        for (int i = t; i < cnt; i += 64) if (keys[i] == best) keys[i] = 0ull;
        if (t == 0) sel[p] = best;
        __syncthreads();
    }
    if (t < kk) {
        unsigned long long bb = sel[t];
        float v = __uint_as_float((unsigned)(bb >> 32));
        int n = (int)(0xFFFFFFFFull - (bb & 0xFFFFFFFFull));
        if (v == maxm[(size_t)b * NN + n]) atomicMin(&tgt[(size_t)b * NN + n], m);
    }
}

// ---------- K_fg: fg accumulation + fused finalize (last block writes out) ----
__global__ __launch_bounds__(256) void k_fg(const int*   __restrict__ tgt,
                                            const int*   __restrict__ gl,
                                            const float* __restrict__ gb,
                                            const float* __restrict__ ps,
                                            const float* __restrict__ pbb,
                                            const float* __restrict__ maxm,
                                            float* __restrict__ accum,
                                            float* __restrict__ out) {
    int i = blockIdx.x * 256 + threadIdx.x;   // i in [0, B*N)
    int t = threadIdx.x;
    float vdot = 0.f, vbox = 0.f, vfg = 0.f;
    int tg = tgt[i];
    if (tg < MM) {
        int b = i / NN;
        int lab = gl[b * MM + tg];
        float x = ps[(size_t)i * NCC + lab];
        float mm = maxm[i];
        float4 p = *(const float4*)(pbb + (size_t)i * 4);
        const float* g = gb + ((size_t)b * MM + tg) * 4;
        float a1 = (p.z - p.x) * (p.w - p.y);
        float a2 = (g[2] - g[0]) * (g[3] - g[1]);
        float iw = fmaxf(fminf(p.z, g[2]) - fmaxf(p.x, g[0]), 0.f);
        float ih = fmaxf(fminf(p.w, g[3]) - fmaxf(p.y, g[1]), 0.f);
        float inter = iw * ih;
        float iou = inter / (a1 + a2 - inter + 1e-16f);
        vdot = x * mm; vbox = 1.0f - iou; vfg = 1.0f;
    }
    #pragma unroll
    for (int off = 32; off > 0; off >>= 1) {
        vdot += __shfl_down(vdot, off);
        vbox += __shfl_down(vbox, off);
        vfg  += __shfl_down(vfg,  off);
    }
    __shared__ float r[3][4];
    if ((t & 63) == 0) { int wv = t >> 6; r[0][wv] = vdot; r[1][wv] = vbox; r[2][wv] = vfg; }
    __syncthreads();
    if (t < 3) {
        float s = r[t][0] + r[t][1] + r[t][2] + r[t][3];
        if (s != 0.f) atomicAdd(&accum[1 + t], s);
    }
    __syncthreads();
    __threadfence();
    if (t == 0) {
        int old = atomicAdd((int*)&accum[7], 1);
        if (old == (int)gridDim.x - 1) {   // last block finalizes
            float S0  = atomicAdd(&accum[0], 0.f);
            float dot = atomicAdd(&accum[1], 0.f);
            float box = atomicAdd(&accum[2], 0.f);
            float fg  = atomicAdd(&accum[3], 0.f);
            float ts  = fmaxf(fg, 1.0f);
            float cls = (S0 - dot) / ts;
            float lb  = (fg > 0.f) ? box / fg : 0.f;
            out[0] = cls + 1.5f * lb;
        }
    }
}

// ---------- launch ----------
extern "C" void kernel_launch(void* const* d_in, const int* in_sizes, int n_in,
                              void* d_out, int out_size, void* d_ws, size_t ws_size,
                              hipStream_t stream) {
    const float* ps = (const float*)d_in[0];   // pred_scores (B,N,NC)
    const float* pd = (const float*)d_in[1];   // pred_dist   (B,N,64)
    const int*   gl = (const int*)  d_in[2];   // gt_labels   (B,M,1)
    const float* gb = (const float*)d_in[3];   // gt_bboxes   (B,M,4)
    const float* w  = (const float*)d_in[4];   // dfl_weight  (16)

    char* ws = (char*)d_ws;
    constexpr size_t HDR_BYTES  = 8192;                                     // accum+done+cnts
    constexpr size_t PBB_BYTES  = (size_t)BB * NN * 4 * sizeof(float);      // 4.30 MB
    constexpr size_t MAXM_BYTES = (size_t)BB * NN * sizeof(float);          // 1.08 MB
    constexpr size_t TGT_BYTES  = (size_t)BB * NN * sizeof(int);            // 1.08 MB
    constexpr size_t SCS_BYTES  = (size_t)BB * NN * SLOTW * 2;              // 21.5 MB

    float* accum = (float*)ws;                 // [0]=S0 [1]=dot [2]=box [3]=fg [7]=done
    int*   cnts  = (int*)(ws + 64);
    float* pbb   = (float*)(ws + HDR_BYTES);
    float* maxm  = (float*)(ws + HDR_BYTES + PBB_BYTES);
    int*   tgt   = (int*)  (ws + HDR_BYTES + PBB_BYTES + MAXM_BYTES);
    unsigned* scs = (unsigned*)(ws + HDR_BYTES + PBB_BYTES + MAXM_BYTES + TGT_BYTES);
    unsigned long long* lists =
        (unsigned long long*)(ws + HDR_BYTES + PBB_BYTES + MAXM_BYTES + TGT_BYTES + SCS_BYTES);

    hipMemsetAsync(ws, 0, HDR_BYTES, stream);  // accum + done + cnts in one node

    dim3 gs((NN + 63) / 64, BB);
    k_score<<<gs, 256, 0, stream>>>(ps, pd, gl, w, pbb, scs, accum);
    dim3 ga((NN + 127) / 128, BB);
    k_align<<<ga, 256, 0, stream>>>(scs, gl, gb, pbb, maxm, cnts, lists, tgt);
    k_topk<<<BB * MM, 64, 0, stream>>>(lists, cnts, maxm, tgt);
    k_fg<<<BB * NN / 256, 256, 0, stream>>>(tgt, gl, gb, ps, pbb, maxm, accum, (float*)d_out);
}

// Round 8
// 277.278 us; speedup vs baseline: 1.0052x; 1.0052x over previous
//
#include <hip/hip_runtime.h>
#include <cstdint>
#include <cstddef>

#define BB 32
#define NN 8400
#define NCC 80
#define MM 40
#define RM 16
#define TOPKK 10
#define CAP 2048      // max positives per (b,m) global list
#define SEG 32        // LDS stage slots per m per 128-anchor block
#define SLOTW 40      // dense slot width (halfwords) in global scs
#define SLOTP 42      // padded LDS halfword stride in k_align (21 dwords, gcd(21,32)=1)

typedef const __attribute__((address_space(1))) void GV;
typedef __attribute__((address_space(3))) void LV;

// ---------- helpers ----------
__device__ __forceinline__ void anchor_xy(int n, float& ax, float& ay) {
    int s, x, y;
    if (n < 6400)      { s = 8;  y = n / 80;            x = n - y * 80; }
    else if (n < 8000) { int i = n - 6400; s = 16; y = i / 40; x = i - y * 40; }
    else               { int i = n - 8000; s = 32; y = i / 20; x = i - y * 20; }
    ax = ((float)x + 0.5f) * (float)s;
    ay = ((float)y + 0.5f) * (float)s;
}

// ---------- K_score: streaming pass over ps+pd ----------
// grid: (132, B) x 256 thr; tile = 64 anchors. ps tile staged via async
// global_load_lds (no VGPR cost -> ~20KB in flight per block; r7 showed the
// allocator sinks register-batched loads to VGPR=28 leaving ~2 in flight).
// pd via registers (consumed by DFL before the barrier). No dedup: duplicate
// labels give bit-identical sigmoids, slots are m-indexed.
__global__ __launch_bounds__(256) void k_score(const float* __restrict__ ps,
                                               const float* __restrict__ pd,
                                               const int*   __restrict__ gl,
                                               const float* __restrict__ w,
                                               float* __restrict__ pbb,
                                               unsigned* __restrict__ scs,
                                               float* __restrict__ accum) {
    __shared__ float lds_ps[64 * 80];      // 20 KB, linear copy of the ps tile
    __shared__ float lt[256];              // DFL ltrb staging
    __shared__ int   glab[MM];
    __shared__ float redf[4];
    const int b  = blockIdx.y;
    const int n0 = blockIdx.x * 64;
    const int t  = threadIdx.x;
    const int lane = t & 63, wv = t >> 6;

    // ---- pd register loads first (older in vmcnt queue than ps async) ----
    const int a = t >> 2, side = t & 3;
    const int na = min(n0 + a, NN - 1);
    const float* pp = pd + (((size_t)(b * NN + na)) * 4 + side) * RM;
    float4 d0 = *(const float4*)(pp);
    float4 d1 = *(const float4*)(pp + 4);
    float4 d2 = *(const float4*)(pp + 8);
    float4 d3 = *(const float4*)(pp + 12);

    // ---- async ps tile -> LDS: 20 chunks x 1KB, 5 per wave ----
    {
        const size_t TOT = (size_t)BB * NN * NCC;
        const size_t tbase = (size_t)(b * NN + n0) * NCC;
        #pragma unroll
        for (int i = 0; i < 5; i++) {
            int chunk = wv + 4 * i;                    // [0,20)
            size_t gfl = tbase + (size_t)chunk * 256 + (size_t)lane * 4;
            if (gfl > TOT - 4) gfl = TOT - 4;          // clamp, keeps 16B align
            __builtin_amdgcn_global_load_lds((GV*)(ps + gfl),
                                             (LV*)(&lds_ps[chunk * 256]), 16, 0, 0);
        }
    }

    if (t < MM) glab[t] = gl[b * MM + t];

    // ---- DFL softmax-dot (covers ps in-flight latency) ----
    {
        float x[RM] = {d0.x,d0.y,d0.z,d0.w, d1.x,d1.y,d1.z,d1.w,
                       d2.x,d2.y,d2.z,d2.w, d3.x,d3.y,d3.z,d3.w};
        float mx = x[0];
        #pragma unroll
        for (int i = 1; i < RM; i++) mx = fmaxf(mx, x[i]);
        float s = 0.f, d = 0.f;
        #pragma unroll
        for (int i = 0; i < RM; i++) {
            float e = __builtin_amdgcn_exp2f((x[i] - mx) * 1.44269504f);
            s += e; d += e * w[i];
        }
        lt[t] = d * __builtin_amdgcn_rcpf(s);
    }
    __syncthreads();   // drains async ps loads (vmcnt0+barrier); lt/glab visible

    if (t < 64) {
        int n = n0 + t;
        float ax, ay; anchor_xy(min(n, NN - 1), ax, ay);
        float4 l4 = *(const float4*)&lt[t * 4];
        if (n < NN)
            *(float4*)(pbb + (size_t)(b * NN + n) * 4) =
                make_float4(ax - l4.x, ay - l4.y, ax + l4.z, ay + l4.w);
    }

    // ---- phase A: softplus over all 5120 tile elements (from LDS) ----
    float sp = 0.f;
    #pragma unroll
    for (int k = 0; k < 5; k++) {
        int f = t + k * 256;                 // float4 index in [0,1280)
        int row = f / 20;
        float vmask = (n0 + row < NN) ? 1.f : 0.f;
        float4 v = ((const float4*)lds_ps)[f];
        float xs[4] = {v.x, v.y, v.z, v.w};
        #pragma unroll
        for (int j = 0; j < 4; j++) {
            float x = xs[j];
            float e = __builtin_amdgcn_exp2f(-1.44269504f * fabsf(x));
            sp += vmask * (fmaxf(x, 0.f) + 0.69314718f * __builtin_amdgcn_logf(1.0f + e));
        }
    }

    // ---- phase B: sqrt(sigmoid) for the 40 label slots, dword-packed ----
    typedef _Float16 h2 __attribute__((ext_vector_type(2)));
    size_t gbase = (size_t)(b * NN + n0) * 20;
    #pragma unroll
    for (int k = 0; k < 5; k++) {
        int e = t + k * 256;                 // dword index in [0,1280)
        int aa = e / 20, sp2 = e % 20;
        int c0 = glab[2 * sp2], c1 = glab[2 * sp2 + 1];
        float x0 = lds_ps[aa * 80 + c0];
        float x1 = lds_ps[aa * 80 + c1];
        float e0 = __builtin_amdgcn_exp2f(-1.44269504f * fabsf(x0));
        float e1 = __builtin_amdgcn_exp2f(-1.44269504f * fabsf(x1));
        float r0 = __builtin_amdgcn_rcpf(1.0f + e0);
        float r1 = __builtin_amdgcn_rcpf(1.0f + e1);
        float s0 = (x0 >= 0.f) ? r0 : e0 * r0;
        float s1 = (x1 >= 0.f) ? r1 : e1 * r1;
        h2 hv;
        hv.x = (_Float16)__builtin_amdgcn_sqrtf(s0);
        hv.y = (_Float16)__builtin_amdgcn_sqrtf(s1);
        if (n0 + aa < NN) scs[gbase + e] = __builtin_bit_cast(unsigned, hv);
    }

    // softplus block reduction -> one atomic
    #pragma unroll
    for (int off = 32; off > 0; off >>= 1) sp += __shfl_down(sp, off);
    if ((t & 63) == 0) redf[t >> 6] = sp;
    __syncthreads();
    if (t == 0) atomicAdd(accum, redf[0] + redf[1] + redf[2] + redf[3]);
}

// ---------- K_align: align + sparse push from precomputed tiles ----------
// grid: (66, B) x 256 thr; tile = 128 anchors. slots m-indexed (no dedup).
__global__ __launch_bounds__(256) void k_align(const unsigned* __restrict__ scs,
                                               const float* __restrict__ gb,
                                               const float* __restrict__ pbb,
                                               float* __restrict__ maxm,
                                               int*   __restrict__ cnts,
                                               unsigned long long* __restrict__ lists,
                                               int*   __restrict__ tgt) {
    __shared__ _Float16 sst[128 * SLOTP];            // 10.75 KB padded
    __shared__ float4 box[128];
    __shared__ float  gtb[MM * 4];
    __shared__ unsigned long long stage[MM * SEG];   // 10.24 KB
    __shared__ int    scnt[MM];
    __shared__ int    baseLoc[MM];
    __shared__ float  cm[256];
    const int b  = blockIdx.y;
    const int n0 = blockIdx.x * 128;
    const int t  = threadIdx.x;
    const int bm0 = b * MM;

    // issue tile loads up front
    unsigned sd[10];
    #pragma unroll
    for (int k = 0; k < 10; k++) {
        int f = t + k * 256;                         // [0,2560)
        int row = f / 20, cd = f - row * 20;
        int rc = min(n0 + row, NN - 1);
        sd[k] = scs[(size_t)(b * NN + rc) * 20 + cd];
    }
    float4 bx4 = make_float4(0,0,0,0);
    if (t < 128) bx4 = *(const float4*)(pbb + (size_t)(b * NN + min(n0 + t, NN - 1)) * 4);

    if (t < 128 && n0 + t < NN) tgt[(size_t)b * NN + n0 + t] = 0x7F7F7F7F;
    if (t < MM * 4)              gtb[t] = gb[b * MM * 4 + t];
    if (t >= 192 && t < 192+MM)  scnt[t - 192] = 0;
    #pragma unroll
    for (int k = 0; k < 10; k++) {
        int f = t + k * 256;
        int row = f / 20, cd = f - row * 20;
        ((unsigned*)sst)[row * 21 + cd] = sd[k];     // halfword stride 42
    }
    if (t < 128) box[t] = bx4;
    __syncthreads();

    // ---- align loop: 20 gts per thread-half; LDS-staged positive push ----
    const int nloc = t & 127;
    const int n    = n0 + nloc;
    const int mb   = (t >> 7) * 20;
    const bool valid = (n < NN);
    float cmax = -INFINITY;
    float4 p4 = box[nloc];
    const float px1 = p4.x, py1 = p4.y, px2 = p4.z, py2 = p4.w;
    const float a1 = (px2 - px1) * (py2 - py1);
    #pragma unroll
    for (int j = 0; j < 20; j++) {
        int m = mb + j;
        float gx1 = gtb[m*4+0], gy1 = gtb[m*4+1], gx2 = gtb[m*4+2], gy2 = gtb[m*4+3];
        float a2 = (gx2 - gx1) * (gy2 - gy1);
        float iw = fmaxf(fminf(px2, gx2) - fmaxf(px1, gx1), 0.f);
        float ih = fmaxf(fminf(py2, gy2) - fmaxf(py1, gy1), 0.f);
        float inter = iw * ih;
        float iou = fmaxf(inter * __builtin_amdgcn_rcpf(a1 + a2 - inter + 1e-16f), 0.f);
        float al = 0.f;
        if (valid) {
            float ssq = (float)sst[nloc * SLOTP + m];   // sqrt(sigmoid)
            float i2 = iou * iou;
            al = ssq * (i2 * i2 * i2);
        }
        cmax = fmaxf(cmax, al);
        if (al > 1e-9f) {
            unsigned long long key =
                ((unsigned long long)__float_as_uint(al) << 32) | (unsigned)n;
            int li = atomicAdd(&scnt[m], 1);
            if (li < SEG) stage[m * SEG + li] = key;
            else {                       // rare overflow: direct global push
                int gi = atomicAdd(&cnts[bm0 + m], 1);
                if (gi < CAP) lists[((size_t)(bm0 + m)) * CAP + gi] = key;
            }
        }
    }
    cm[t] = cmax;
    __syncthreads();
    if (t < 128 && valid) maxm[(size_t)b * NN + n] = fmaxf(cm[t], cm[t + 128]);
    if (t < MM) {
        int ns = min(scnt[t], SEG);
        baseLoc[t] = (ns > 0) ? atomicAdd(&cnts[bm0 + t], ns) : 0;
    }
    __syncthreads();
    #pragma unroll
    for (int f = t; f < MM * SEG; f += 256) {
        int m = f >> 5, i = f & 31;
        if (i < min(scnt[m], SEG)) {
            int gi = baseLoc[m] + i;
            if (gi < CAP) lists[((size_t)(bm0 + m)) * CAP + gi] = stage[f];
        }
    }
}

// ---------- K_topk: top-10 of compacted positives, LDS-only passes ----------
__global__ __launch_bounds__(64) void k_topk(const unsigned long long* __restrict__ lists,
                                             const int*   __restrict__ cnts,
                                             const float* __restrict__ maxm,
                                             int* __restrict__ tgt) {
    __shared__ unsigned long long keys[CAP];
    __shared__ unsigned long long sel[TOPKK];
    const int bm = blockIdx.x, b = bm / MM, m = bm % MM, t = threadIdx.x;
    int cnt = min(cnts[bm], CAP);
    int kk = min(TOPKK, cnt);
    for (int i = t; i < cnt; i += 64) {
        unsigned long long L = lists[(size_t)bm * CAP + i];
        keys[i] = (L & 0xFFFFFFFF00000000ull) | (0xFFFFFFFFull - (L & 0xFFFFFFFFull));
    }
    __syncthreads();
    for (int p = 0; p < kk; p++) {
        unsigned long long best = 0ull;
        for (int i = t; i < cnt; i += 64) best = keys[i] > best ? keys[i] : best;
        #pragma unroll
        for (int off = 32; off > 0; off >>= 1) {
            unsigned long long o = __shfl_xor(best, off);
            best = o > best ? o : best;
        }
        for (int i = t; i < cnt; i += 64) if (keys[i] == best) keys[i] = 0ull;
        if (t == 0) sel[p] = best;
        __syncthreads();
    }
    if (t < kk) {
        unsigned long long bb = sel[t];
        float v = __uint_as_float((unsigned)(bb >> 32));
        int n = (int)(0xFFFFFFFFull - (bb & 0xFFFFFFFFull));
        if (v == maxm[(size_t)b * NN + n]) atomicMin(&tgt[(size_t)b * NN + n], m);
    }
}

// ---------- K_fg: fg accumulation + fused finalize (last block writes out) ----
__global__ __launch_bounds__(256) void k_fg(const int*   __restrict__ tgt,
                                            const int*   __restrict__ gl,
                                            const float* __restrict__ gb,
                                            const float* __restrict__ ps,
                                            const float* __restrict__ pbb,
                                            const float* __restrict__ maxm,
                                            float* __restrict__ accum,
                                            float* __restrict__ out) {
    int i = blockIdx.x * 256 + threadIdx.x;   // i in [0, B*N)
    int t = threadIdx.x;
    float vdot = 0.f, vbox = 0.f, vfg = 0.f;
    int tg = tgt[i];
    if (tg < MM) {
        int b = i / NN;
        int lab = gl[b * MM + tg];
        float x = ps[(size_t)i * NCC + lab];
        float mm = maxm[i];
        float4 p = *(const float4*)(pbb + (size_t)i * 4);
        const float* g = gb + ((size_t)b * MM + tg) * 4;
        float a1 = (p.z - p.x) * (p.w - p.y);
        float a2 = (g[2] - g[0]) * (g[3] - g[1]);
        float iw = fmaxf(fminf(p.z, g[2]) - fmaxf(p.x, g[0]), 0.f);
        float ih = fmaxf(fminf(p.w, g[3]) - fmaxf(p.y, g[1]), 0.f);
        float inter = iw * ih;
        float iou = inter / (a1 + a2 - inter + 1e-16f);
        vdot = x * mm; vbox = 1.0f - iou; vfg = 1.0f;
    }
    #pragma unroll
    for (int off = 32; off > 0; off >>= 1) {
        vdot += __shfl_down(vdot, off);
        vbox += __shfl_down(vbox, off);
        vfg  += __shfl_down(vfg,  off);
    }
    __shared__ float r[3][4];
    if ((t & 63) == 0) { int wv = t >> 6; r[0][wv] = vdot; r[1][wv] = vbox; r[2][wv] = vfg; }
    __syncthreads();
    if (t < 3) {
        float s = r[t][0] + r[t][1] + r[t][2] + r[t][3];
        if (s != 0.f) atomicAdd(&accum[1 + t], s);
    }
    __syncthreads();
    __threadfence();
    if (t == 0) {
        int old = atomicAdd((int*)&accum[7], 1);
        if (old == (int)gridDim.x - 1) {   // last block finalizes
            float S0  = atomicAdd(&accum[0], 0.f);
            float dot = atomicAdd(&accum[1], 0.f);
            float box = atomicAdd(&accum[2], 0.f);
            float fg  = atomicAdd(&accum[3], 0.f);
            float ts  = fmaxf(fg, 1.0f);
            float cls = (S0 - dot) / ts;
            float lb  = (fg > 0.f) ? box / fg : 0.f;
            out[0] = cls + 1.5f * lb;
        }
    }
}

// ---------- launch ----------
extern "C" void kernel_launch(void* const* d_in, const int* in_sizes, int n_in,
                              void* d_out, int out_size, void* d_ws, size_t ws_size,
                              hipStream_t stream) {
    const float* ps = (const float*)d_in[0];   // pred_scores (B,N,NC)
    const float* pd = (const float*)d_in[1];   // pred_dist   (B,N,64)
    const int*   gl = (const int*)  d_in[2];   // gt_labels   (B,M,1)
    const float* gb = (const float*)d_in[3];   // gt_bboxes   (B,M,4)
    const float* w  = (const float*)d_in[4];   // dfl_weight  (16)

    char* ws = (char*)d_ws;
    constexpr size_t HDR_BYTES  = 8192;                                     // accum+done+cnts
    constexpr size_t PBB_BYTES  = (size_t)BB * NN * 4 * sizeof(float);      // 4.30 MB
    constexpr size_t MAXM_BYTES = (size_t)BB * NN * sizeof(float);          // 1.08 MB
    constexpr size_t TGT_BYTES  = (size_t)BB * NN * sizeof(int);            // 1.08 MB
    constexpr size_t SCS_BYTES  = (size_t)BB * NN * SLOTW * 2;              // 21.5 MB

    float* accum = (float*)ws;                 // [0]=S0 [1]=dot [2]=box [3]=fg [7]=done
    int*   cnts  = (int*)(ws + 64);
    float* pbb   = (float*)(ws + HDR_BYTES);
    float* maxm  = (float*)(ws + HDR_BYTES + PBB_BYTES);
    int*   tgt   = (int*)  (ws + HDR_BYTES + PBB_BYTES + MAXM_BYTES);
    unsigned* scs = (unsigned*)(ws + HDR_BYTES + PBB_BYTES + MAXM_BYTES + TGT_BYTES);
    unsigned long long* lists =
        (unsigned long long*)(ws + HDR_BYTES + PBB_BYTES + MAXM_BYTES + TGT_BYTES + SCS_BYTES);

    hipMemsetAsync(ws, 0, HDR_BYTES, stream);  // accum + done + cnts in one node

    dim3 gs((NN + 63) / 64, BB);
    k_score<<<gs, 256, 0, stream>>>(ps, pd, gl, w, pbb, scs, accum);
    dim3 ga((NN + 127) / 128, BB);
    k_align<<<ga, 256, 0, stream>>>(scs, gb, pbb, maxm, cnts, lists, tgt);
    k_topk<<<BB * MM, 64, 0, stream>>>(lists, cnts, maxm, tgt);
    k_fg<<<BB * NN / 256, 256, 0, stream>>>(tgt, gl, gb, ps, pbb, maxm, accum, (float*)d_out);
}